// Round 1
// 261.335 us; speedup vs baseline: 1.0331x; 1.0331x over previous
//
#include <hip/hip_runtime.h>
#include <stdint.h>

typedef __bf16 bf16_t;
typedef bf16_t bf16x4 __attribute__((ext_vector_type(4)));
typedef bf16_t bf16x8 __attribute__((ext_vector_type(8)));
typedef float f32x4 __attribute__((ext_vector_type(4)));

#define DIM 256
#define NNODES 50000

// ---------------- edge dtype detection (int64 vs int32) ----------------
__global__ void detect_kernel(const int* __restrict__ ei, int* __restrict__ flags) {
    __shared__ int s_zero;
    if (threadIdx.x == 0) s_zero = 0;
    __syncthreads();
    int z = (ei[2 * threadIdx.x + 1] == 0) ? 1 : 0;   // odd words: int64 high halves == 0
    atomicAdd(&s_zero, z);
    __syncthreads();
    if (threadIdx.x == 0) flags[0] = (s_zero > 128) ? 1 : 0;
}

__device__ __forceinline__ int load_edge(const int* __restrict__ ei, int E, int f64,
                                         int which /*0=src,1=dst*/, int e) {
    int v = f64 ? ei[(size_t)which * 2 * E + 2 * (size_t)e]   // int64 low word (LE)
                : ei[(size_t)which * E + (size_t)e];
    return min(max(v, 0), NNODES - 1);
}

// ---------------- CSR build ----------------

__global__ void hist_kernel(const int* __restrict__ ei, int E, const int* __restrict__ flags,
                            int* __restrict__ counts) {
    int e = blockIdx.x * blockDim.x + threadIdx.x;
    if (e < E) atomicAdd(&counts[load_edge(ei, E, flags[0], 1, e)], 1);
}

__global__ __launch_bounds__(256) void scanA_kernel(const int* __restrict__ counts,
                                                    int* __restrict__ offsets,
                                                    int* __restrict__ bsums, int n) {
    __shared__ int sm[256];
    int b = blockIdx.x, t = threadIdx.x;
    int idx = b * 256 + t;
    int v = (idx < n) ? counts[idx] : 0;
    sm[t] = v;
    __syncthreads();
    #pragma unroll
    for (int off = 1; off < 256; off <<= 1) {
        int u = (t >= off) ? sm[t - off] : 0;
        __syncthreads();
        sm[t] += u;
        __syncthreads();
    }
    if (idx < n) offsets[idx + 1] = sm[t];
    if (t == 255) bsums[b] = sm[255];
}

__global__ __launch_bounds__(256) void scanB_kernel(int* __restrict__ bsums, int nb) {
    __shared__ int sm[256];
    int t = threadIdx.x;
    int v = (t < nb) ? bsums[t] : 0;
    sm[t] = v;
    __syncthreads();
    #pragma unroll
    for (int off = 1; off < 256; off <<= 1) {
        int u = (t >= off) ? sm[t - off] : 0;
        __syncthreads();
        sm[t] += u;
        __syncthreads();
    }
    if (t < nb) bsums[t] = sm[t] - v;
}

__global__ __launch_bounds__(256) void scanC_kernel(const int* __restrict__ counts,
                                                    const int* __restrict__ bsums,
                                                    int* __restrict__ offsets,
                                                    float* __restrict__ dinv,
                                                    int* __restrict__ cursor, int n) {
    int b = blockIdx.x;
    int idx = b * 256 + threadIdx.x;
    if (idx == 0) offsets[0] = 0;
    if (idx < n) {
        int incl = offsets[idx + 1] + bsums[b];
        offsets[idx + 1] = incl;
        cursor[idx] = incl - counts[idx];
        dinv[idx] = rsqrtf((float)(counts[idx] + 1));  // +1 self-loop
    }
}

// csr_e[pos] = {src, norm} packed 8B: one coalescable load per edge on the consumer side.
__global__ void scatter_kernel(const int* __restrict__ ei, int E, const int* __restrict__ flags,
                               const float* __restrict__ dinv, int* __restrict__ cursor,
                               int2* __restrict__ csr_e) {
    int e = blockIdx.x * blockDim.x + threadIdx.x;
    if (e < E) {
        int s = load_edge(ei, E, flags[0], 0, e);
        int d = load_edge(ei, E, flags[0], 1, e);
        int pos = atomicAdd(&cursor[d], 1);
        if (pos >= 0 && pos < E) {
            int2 v;
            v.x = s;
            v.y = __float_as_int(dinv[s] * dinv[d]);
            csr_e[pos] = v;
        }
    }
}

// ---------------- weight prep: fp32 W[k][n] -> fragment-order bf16 Wf ----------------
// Wf layout: slice s = k>>5 (8 slices); frag f = nt*64 + quad*16 + m where
// n = nt*16+m, k = s*32 + quad*8 + j. Flat short index: s*8192 + f*8 + j.
// This makes LDS staging a sequential copy and B-frag reads conflict-free.

__global__ void convert_w_kernel(const float* __restrict__ W1, const float* __restrict__ W2,
                                 bf16_t* __restrict__ Wf1, bf16_t* __restrict__ Wf2) {
    const float* W = blockIdx.y ? W2 : W1;
    bf16_t* Wf = blockIdx.y ? Wf2 : Wf1;
    int k = blockIdx.x, n = threadIdx.x;      // read W[k][n] coalesced per block
    int s = k >> 5, quad = (k >> 3) & 3, j = k & 7;
    int nt = n >> 4, m = n & 15;
    Wf[s * 8192 + (nt * 64 + quad * 16 + m) * 8 + j] = (bf16_t)W[k * DIM + n];
}

// ---------------- GEMM: H[M,256](bf16) = X[M,256] @ W ----------------
// 1 row-tile (16 rows) per wave, 4 waves/block -> 64 rows/block, grid = 782.
// W staged per 32-k slice in fragment order: 16 KB LDS, zero bank conflicts.
// acc[16] = 64 VGPRs; __launch_bounds__(256,4) targets 4 waves/SIMD.

template <bool F32A>
__global__ __launch_bounds__(256, 4) void gemm_kernel(const void* __restrict__ Xv,
                                                      const bf16_t* __restrict__ Wf,
                                                      bf16_t* __restrict__ H, int tiles) {
    __shared__ bf16_t sB[8192];               // 256n x 32k slice, fragment order
    int tid = threadIdx.x;
    int wave = tid >> 6, lane = tid & 63;
    int m = lane & 15, quad = lane >> 4;
    int tile = blockIdx.x * 4 + wave;
    bool active = tile < tiles;
    int arow = (min(tile, tiles - 1)) * 16 + m;   // clamped; store predicated below

    f32x4 acc[16] = {};

    for (int s = 0; s < 8; s++) {
        __syncthreads();                      // protect previous slice's reads
        {
            const bf16x8* g = (const bf16x8*)Wf + s * 1024;
            bf16x8* d = (bf16x8*)sB;
            #pragma unroll
            for (int it = 0; it < 4; it++) d[tid + it * 256] = g[tid + it * 256];
        }
        __syncthreads();

        // A fragment: A[m=lane&15][k = s*32 + quad*8 + j]
        bf16x8 a;
        if (F32A) {
            const f32x4* xp = (const f32x4*)((const float*)Xv + (size_t)arow * DIM + s * 32 + quad * 8);
            f32x4 x0 = xp[0], x1 = xp[1];
            #pragma unroll
            for (int j = 0; j < 4; j++) { a[j] = (bf16_t)x0[j]; a[j + 4] = (bf16_t)x1[j]; }
        } else {
            a = *(const bf16x8*)((const bf16_t*)Xv + (size_t)arow * DIM + s * 32 + quad * 8);
        }

        #pragma unroll
        for (int nt = 0; nt < 16; nt++) {
            bf16x8 b = *(const bf16x8*)(sB + nt * 512 + lane * 8);  // sequential: no conflicts
            acc[nt] = __builtin_amdgcn_mfma_f32_16x16x32_bf16(a, b, acc[nt], 0, 0, 0);
        }
    }

    if (active) {
        int rowb = tile * 16 + quad * 4;
        #pragma unroll
        for (int nt = 0; nt < 16; nt++) {
            #pragma unroll
            for (int r = 0; r < 4; r++) {
                H[(size_t)(rowb + r) * DIM + nt * 16 + m] = (bf16_t)acc[nt][r];
            }
        }
    }
}

// ---------------- Aggregation: bf16 H gather, fp32 accumulate ----------------
// One node per wave (64 lanes x bf16x4 = 512B row). Latency-hiding scheme:
//  * lane j prefetches edge j's packed {src,norm} int2 (one coalesced 8B load
//    per 64 edges) instead of 64 lanes re-loading the same scalar per edge;
//  * wave walks edges via readlane -> src index is a wave-uniform SGPR, so the
//    gather has NO dependent index load on its critical path;
//  * gathers issued in batches of 8 (8 independent loads in flight/lane);
//    short batches padded with {self-row, w=0} -> cache-hot exact no-op.
// Summation order over e is unchanged vs the previous version.

template <bool OUT_BF16>
__global__ __launch_bounds__(256) void aggregate_kernel(const bf16_t* __restrict__ H,
                                                        const int* __restrict__ offsets,
                                                        const int2* __restrict__ csr_e,
                                                        const float* __restrict__ dinv,
                                                        const float* __restrict__ bias,
                                                        void* __restrict__ outv, int n) {
    int g = threadIdx.x >> 6;
    int l = threadIdx.x & 63;
    int i = blockIdx.x * 4 + g;
    if (i >= n) return;
    float dii = dinv[i];

    auto cvt = [](bf16x4 v) -> f32x4 {
        f32x4 r;
        #pragma unroll
        for (int j = 0; j < 4; j++) r[j] = (float)v[j];
        return r;
    };

    f32x4 acc = cvt(*(const bf16x4*)(H + (size_t)i * DIM + l * 4)) * (dii * dii);
    int e0 = offsets[i], e1 = offsets[i + 1];

    for (int e = e0; e < e1; e += 64) {
        int rem = e1 - e;
        int2 ed;
        if (l < rem) {
            ed = csr_e[e + l];
        } else {
            ed.x = i;                 // pad: self row (cache-hot), zero weight
            ed.y = 0;                 // 0.0f
        }
        int nb = rem < 64 ? rem : 64;
        for (int b = 0; b < nb; b += 8) {
            bf16x4 h[8];
            float w[8];
            #pragma unroll
            for (int jj = 0; jj < 8; jj++) {
                int s = (int)__builtin_amdgcn_readlane((unsigned)ed.x, (unsigned)(b + jj));
                unsigned wb = __builtin_amdgcn_readlane((unsigned)ed.y, (unsigned)(b + jj));
                w[jj] = __uint_as_float(wb);
                h[jj] = *(const bf16x4*)(H + (size_t)s * DIM + l * 4);
            }
            #pragma unroll
            for (int jj = 0; jj < 8; jj++) acc += cvt(h[jj]) * w[jj];
        }
    }

    acc += *(const f32x4*)(bias + l * 4);
    #pragma unroll
    for (int j = 0; j < 4; j++) acc[j] = fmaxf(acc[j], 0.0f);

    if (OUT_BF16) {
        bf16x4 o;
        #pragma unroll
        for (int j = 0; j < 4; j++) o[j] = (bf16_t)acc[j];
        *(bf16x4*)((bf16_t*)outv + (size_t)i * DIM + l * 4) = o;
    } else {
        *(f32x4*)((float*)outv + (size_t)i * DIM + l * 4) = acc;
    }
}

// ---------------- launch ----------------

extern "C" void kernel_launch(void* const* d_in, const int* in_sizes, int n_in,
                              void* d_out, int out_size, void* d_ws, size_t ws_size,
                              hipStream_t stream) {
    const float* x  = (const float*)d_in[0];
    const int*   ei = (const int*)d_in[1];
    const float* W1 = (const float*)d_in[2];
    const float* b1 = (const float*)d_in[3];
    const float* W2 = (const float*)d_in[4];
    const float* b2 = (const float*)d_in[5];
    float* out = (float*)d_out;

    const int n = NNODES;
    const int E = in_sizes[1] / 2;
    const int nb = (n + 255) / 256;

    char* ws = (char*)d_ws;
    size_t off = 0;
    auto alloc = [&](size_t bytes) -> char* {
        char* p = ws + off;
        off += (bytes + 255) & ~(size_t)255;
        return p;
    };
    int*    flags    = (int*)alloc(256);
    float*  dinv     = (float*)alloc((size_t)n * 4);
    int*    counts   = (int*)alloc((size_t)n * 4);
    int*    offsets  = (int*)alloc((size_t)(n + 1) * 4);
    int*    cursor   = (int*)alloc((size_t)n * 4);
    int*    bsums    = (int*)alloc((size_t)nb * 4);
    int2*   csr_e    = (int2*)alloc((size_t)E * 8);
    bf16_t* Wf1      = (bf16_t*)alloc((size_t)DIM * DIM * 2);
    bf16_t* Wf2      = (bf16_t*)alloc((size_t)DIM * DIM * 2);
    bf16_t* P        = (bf16_t*)alloc((size_t)n * DIM * 2);   // GEMM output (bf16)
    bf16_t* X2       = (bf16_t*)alloc((size_t)n * DIM * 2);   // inter-layer activation (bf16)

    detect_kernel<<<1, 256, 0, stream>>>(ei, flags);
    hipMemsetAsync(counts, 0, (size_t)n * 4, stream);
    hist_kernel<<<(E + 255) / 256, 256, 0, stream>>>(ei, E, flags, counts);
    scanA_kernel<<<nb, 256, 0, stream>>>(counts, offsets, bsums, n);
    scanB_kernel<<<1, 256, 0, stream>>>(bsums, nb);
    scanC_kernel<<<nb, 256, 0, stream>>>(counts, bsums, offsets, dinv, cursor, n);
    scatter_kernel<<<(E + 255) / 256, 256, 0, stream>>>(ei, E, flags, dinv, cursor, csr_e);

    convert_w_kernel<<<dim3(DIM, 2), DIM, 0, stream>>>(W1, W2, Wf1, Wf2);

    int tiles = (n + 15) / 16;                 // 3125 (exact: 50000 = 16*3125)
    int gemm_blocks = (tiles + 3) / 4;         // 782
    int agg_blocks = n / 4;                    // 12500

    gemm_kernel<true><<<gemm_blocks, 256, 0, stream>>>(x, Wf1, P, tiles);
    aggregate_kernel<true><<<agg_blocks, 256, 0, stream>>>(P, offsets, csr_e, dinv, b1, X2, n);
    gemm_kernel<false><<<gemm_blocks, 256, 0, stream>>>(X2, Wf2, P, tiles);
    aggregate_kernel<false><<<agg_blocks, 256, 0, stream>>>(P, offsets, csr_e, dinv, b2, out, n);
}

// Round 2
// 258.967 us; speedup vs baseline: 1.0426x; 1.0091x over previous
//
#include <hip/hip_runtime.h>
#include <stdint.h>

typedef __bf16 bf16_t;
typedef bf16_t bf16x4 __attribute__((ext_vector_type(4)));
typedef bf16_t bf16x8 __attribute__((ext_vector_type(8)));
typedef float f32x4 __attribute__((ext_vector_type(4)));

#define DIM 256
#define NNODES 50000
#define NPANEL 8           // 8 panels x 32 dims; one panel = 50000*32*2B = 3.2MB < 4MiB L2/XCD
#define PDIM 32

// ---------------- edge dtype detection (int64 vs int32), per-wave inline ----------------
// int64 edges: odd 4B words are high halves == 0 for values < 2^31.
__device__ __forceinline__ int detect_f64(const int* __restrict__ ei) {
    int v = ei[2 * (threadIdx.x & 63) + 1];
    unsigned long long m = __ballot(v == 0);
    return __popcll(m) > 32;
}

__device__ __forceinline__ int load_edge(const int* __restrict__ ei, int E, int f64,
                                         int which /*0=src,1=dst*/, int e) {
    int v = f64 ? ei[(size_t)which * 2 * E + 2 * (size_t)e]   // int64 low word (LE)
                : ei[(size_t)which * E + (size_t)e];
    return min(max(v, 0), NNODES - 1);
}

// ---------------- CSR build ----------------

__global__ void hist_kernel(const int* __restrict__ ei, int E, int* __restrict__ counts) {
    int f64 = detect_f64(ei);
    int e = blockIdx.x * blockDim.x + threadIdx.x;
    if (e < E) atomicAdd(&counts[load_edge(ei, E, f64, 1, e)], 1);
}

__global__ __launch_bounds__(256) void scanA_kernel(const int* __restrict__ counts,
                                                    int* __restrict__ offsets,
                                                    int* __restrict__ bsums, int n) {
    __shared__ int sm[256];
    int b = blockIdx.x, t = threadIdx.x;
    int idx = b * 256 + t;
    int v = (idx < n) ? counts[idx] : 0;
    sm[t] = v;
    __syncthreads();
    #pragma unroll
    for (int off = 1; off < 256; off <<= 1) {
        int u = (t >= off) ? sm[t - off] : 0;
        __syncthreads();
        sm[t] += u;
        __syncthreads();
    }
    if (idx < n) offsets[idx + 1] = sm[t];
    if (t == 255) bsums[b] = sm[255];
}

__global__ __launch_bounds__(256) void scanB_kernel(int* __restrict__ bsums, int nb) {
    __shared__ int sm[256];
    int t = threadIdx.x;
    int v = (t < nb) ? bsums[t] : 0;
    sm[t] = v;
    __syncthreads();
    #pragma unroll
    for (int off = 1; off < 256; off <<= 1) {
        int u = (t >= off) ? sm[t - off] : 0;
        __syncthreads();
        sm[t] += u;
        __syncthreads();
    }
    if (t < nb) bsums[t] = sm[t] - v;
}

__global__ __launch_bounds__(256) void scanC_kernel(const int* __restrict__ counts,
                                                    const int* __restrict__ bsums,
                                                    int* __restrict__ offsets,
                                                    float* __restrict__ dinv,
                                                    int* __restrict__ cursor, int n) {
    int b = blockIdx.x;
    int idx = b * 256 + threadIdx.x;
    if (idx == 0) offsets[0] = 0;
    if (idx < n) {
        int incl = offsets[idx + 1] + bsums[b];
        offsets[idx + 1] = incl;
        cursor[idx] = incl - counts[idx];
        dinv[idx] = rsqrtf((float)(counts[idx] + 1));  // +1 self-loop
    }
}

// csr_e[pos] = {src, norm_bits} packed 8B.
__global__ void scatter_kernel(const int* __restrict__ ei, int E,
                               const float* __restrict__ dinv, int* __restrict__ cursor,
                               int2* __restrict__ csr_e) {
    int f64 = detect_f64(ei);
    int e = blockIdx.x * blockDim.x + threadIdx.x;
    if (e < E) {
        int s = load_edge(ei, E, f64, 0, e);
        int d = load_edge(ei, E, f64, 1, e);
        int pos = atomicAdd(&cursor[d], 1);
        if (pos >= 0 && pos < E) {
            int2 v;
            v.x = s;
            v.y = __float_as_int(dinv[s] * dinv[d]);
            csr_e[pos] = v;
        }
    }
}

// ---------------- weight prep: fp32 W[k][n] -> fragment-order bf16 Wf ----------------
// Wf layout: slice s = k>>5 (8 slices); frag f = nt*64 + quad*16 + m where
// n = nt*16+m, k = s*32 + quad*8 + j. Flat short index: s*8192 + f*8 + j.

__global__ void convert_w_kernel(const float* __restrict__ W1, const float* __restrict__ W2,
                                 bf16_t* __restrict__ Wf1, bf16_t* __restrict__ Wf2) {
    const float* W = blockIdx.y ? W2 : W1;
    bf16_t* Wf = blockIdx.y ? Wf2 : Wf1;
    int k = blockIdx.x, n = threadIdx.x;      // read W[k][n] coalesced per block
    int s = k >> 5, quad = (k >> 3) & 3, j = k & 7;
    int nt = n >> 4, m = n & 15;
    Wf[s * 8192 + (nt * 64 + quad * 16 + m) * 8 + j] = (bf16_t)W[k * DIM + n];
}

// ---------------- GEMM: Hp[panel-major](bf16) = X[M,256] @ W ----------------
// Output panel-major: Hp[p][row][32dims], p = col>>5. 1 row-tile (16 rows)/wave,
// 4 waves/block. A input either fp32 row-major (layer 1) or bf16 panel-major (layer 2).

template <bool F32A>
__global__ __launch_bounds__(256, 4) void gemm_kernel(const void* __restrict__ Xv,
                                                      const bf16_t* __restrict__ Wf,
                                                      bf16_t* __restrict__ Hp, int tiles) {
    __shared__ bf16_t sB[8192];               // 256n x 32k slice, fragment order
    int tid = threadIdx.x;
    int wave = tid >> 6, lane = tid & 63;
    int m = lane & 15, quad = lane >> 4;
    int tile = blockIdx.x * 4 + wave;
    bool active = tile < tiles;
    int arow = (min(tile, tiles - 1)) * 16 + m;   // clamped; store predicated below

    f32x4 acc[16] = {};

    for (int s = 0; s < 8; s++) {
        __syncthreads();                      // protect previous slice's reads
        {
            const bf16x8* g = (const bf16x8*)Wf + s * 1024;
            bf16x8* d = (bf16x8*)sB;
            #pragma unroll
            for (int it = 0; it < 4; it++) d[tid + it * 256] = g[tid + it * 256];
        }
        __syncthreads();

        // A fragment: A[m=lane&15][k = s*32 + quad*8 + j]
        bf16x8 a;
        if (F32A) {
            const f32x4* xp = (const f32x4*)((const float*)Xv + (size_t)arow * DIM + s * 32 + quad * 8);
            f32x4 x0 = xp[0], x1 = xp[1];
            #pragma unroll
            for (int j = 0; j < 4; j++) { a[j] = (bf16_t)x0[j]; a[j + 4] = (bf16_t)x1[j]; }
        } else {
            // panel-major bf16: panel s, within-panel offset quad*8 (16B aligned)
            a = *(const bf16x8*)((const bf16_t*)Xv + ((size_t)s * NNODES + arow) * PDIM + quad * 8);
        }

        #pragma unroll
        for (int nt = 0; nt < 16; nt++) {
            bf16x8 b = *(const bf16x8*)(sB + nt * 512 + lane * 8);  // sequential: no conflicts
            acc[nt] = __builtin_amdgcn_mfma_f32_16x16x32_bf16(a, b, acc[nt], 0, 0, 0);
        }
    }

    if (active) {
        int rowb = tile * 16 + quad * 4;
        #pragma unroll
        for (int nt = 0; nt < 16; nt++) {
            size_t pbase = ((size_t)(nt >> 1) * NNODES) * PDIM + (nt & 1) * 16 + m;
            #pragma unroll
            for (int r = 0; r < 4; r++) {
                Hp[pbase + (size_t)(rowb + r) * PDIM] = (bf16_t)acc[nt][r];
            }
        }
    }
}

// ---------------- Aggregation: panel-decomposed, L2-resident gather ----------------
// Block b: panel p = b&7 (round-robin -> all blocks of panel p land on XCD p, whose
// 4MiB L2 holds the whole 3.2MB panel), node chunk = b>>3 (32 nodes/block).
// Wave: 8 groups x 8 lanes; group owns one node, lane owns 4 dims (bf16x4 = 8B).
// Edges: lane c preloads csr_e[e+c]; __shfl broadcasts (src,w) within group;
// 8 independent 8B gathers in flight per lane. Tail padded with {self,0} (no-op).

template <int OUT_BF16P>  // 1: bf16 panel-major out; 0: fp32 row-major out
__global__ __launch_bounds__(256) void aggregate_kernel(const bf16_t* __restrict__ Hp,
                                                        const int* __restrict__ offsets,
                                                        const int2* __restrict__ csr_e,
                                                        const float* __restrict__ dinv,
                                                        const float* __restrict__ bias,
                                                        void* __restrict__ outv, int n) {
    int p = blockIdx.x & 7;
    int chunk = blockIdx.x >> 3;
    int wave = threadIdx.x >> 6, lane = threadIdx.x & 63;
    int g = lane >> 3, c = lane & 7;
    int i = chunk * 32 + wave * 8 + g;
    if (i >= n) return;

    auto cvt = [](bf16x4 v) -> f32x4 {
        f32x4 r;
        #pragma unroll
        for (int j = 0; j < 4; j++) r[j] = (float)v[j];
        return r;
    };

    const bf16_t* Hpan = Hp + (size_t)p * ((size_t)NNODES * PDIM);
    float dii = dinv[i];
    f32x4 acc = cvt(*(const bf16x4*)(Hpan + (size_t)i * PDIM + c * 4)) * (dii * dii);
    int e0 = offsets[i], e1 = offsets[i + 1];

    for (int e = e0; e < e1; e += 8) {
        int2 ed;
        if (e + c < e1) {
            ed = csr_e[e + c];
        } else {
            ed.x = i;                 // pad: self row (L2-hot), zero weight
            ed.y = 0;
        }
        int s[8]; float w[8];
        #pragma unroll
        for (int j = 0; j < 8; j++) {
            int srcLane = (lane & 56) + j;
            s[j] = __shfl(ed.x, srcLane, 64);
            w[j] = __uint_as_float((unsigned)__shfl(ed.y, srcLane, 64));
        }
        bf16x4 h[8];
        #pragma unroll
        for (int j = 0; j < 8; j++) {
            h[j] = *(const bf16x4*)(Hpan + (size_t)s[j] * PDIM + c * 4);
        }
        #pragma unroll
        for (int j = 0; j < 8; j++) acc += cvt(h[j]) * w[j];
    }

    acc += *(const f32x4*)(bias + p * PDIM + c * 4);
    #pragma unroll
    for (int j = 0; j < 4; j++) acc[j] = fmaxf(acc[j], 0.0f);

    if (OUT_BF16P) {
        bf16x4 o;
        #pragma unroll
        for (int j = 0; j < 4; j++) o[j] = (bf16_t)acc[j];
        *(bf16x4*)((bf16_t*)outv + (size_t)p * NNODES * PDIM + (size_t)i * PDIM + c * 4) = o;
    } else {
        *(f32x4*)((float*)outv + (size_t)i * DIM + p * PDIM + c * 4) = acc;
    }
}

// ---------------- launch ----------------

extern "C" void kernel_launch(void* const* d_in, const int* in_sizes, int n_in,
                              void* d_out, int out_size, void* d_ws, size_t ws_size,
                              hipStream_t stream) {
    const float* x  = (const float*)d_in[0];
    const int*   ei = (const int*)d_in[1];
    const float* W1 = (const float*)d_in[2];
    const float* b1 = (const float*)d_in[3];
    const float* W2 = (const float*)d_in[4];
    const float* b2 = (const float*)d_in[5];
    float* out = (float*)d_out;

    const int n = NNODES;
    const int E = in_sizes[1] / 2;
    const int nb = (n + 255) / 256;

    char* ws = (char*)d_ws;
    size_t off = 0;
    auto alloc = [&](size_t bytes) -> char* {
        char* p = ws + off;
        off += (bytes + 255) & ~(size_t)255;
        return p;
    };
    float*  dinv     = (float*)alloc((size_t)n * 4);
    int*    counts   = (int*)alloc((size_t)n * 4);
    int*    offsets  = (int*)alloc((size_t)(n + 1) * 4);
    int*    cursor   = (int*)alloc((size_t)n * 4);
    int*    bsums    = (int*)alloc((size_t)nb * 4);
    int2*   csr_e    = (int2*)alloc((size_t)E * 8);
    bf16_t* Wf1      = (bf16_t*)alloc((size_t)DIM * DIM * 2);
    bf16_t* Wf2      = (bf16_t*)alloc((size_t)DIM * DIM * 2);
    bf16_t* P        = (bf16_t*)alloc((size_t)n * DIM * 2);   // GEMM output, panel-major bf16
    bf16_t* X2       = (bf16_t*)alloc((size_t)n * DIM * 2);   // inter-layer act, panel-major bf16

    hipMemsetAsync(counts, 0, (size_t)n * 4, stream);
    hist_kernel<<<(E + 255) / 256, 256, 0, stream>>>(ei, E, counts);
    scanA_kernel<<<nb, 256, 0, stream>>>(counts, offsets, bsums, n);
    scanB_kernel<<<1, 256, 0, stream>>>(bsums, nb);
    scanC_kernel<<<nb, 256, 0, stream>>>(counts, bsums, offsets, dinv, cursor, n);
    scatter_kernel<<<(E + 255) / 256, 256, 0, stream>>>(ei, E, dinv, cursor, csr_e);

    convert_w_kernel<<<dim3(DIM, 2), DIM, 0, stream>>>(W1, W2, Wf1, Wf2);

    int tiles = (n + 15) / 16;                 // 3125 (exact: 50000 = 16*3125)
    int gemm_blocks = (tiles + 3) / 4;         // 782
    int agg_blocks = NPANEL * ((n + 31) / 32); // 8 * 1563 = 12504

    gemm_kernel<true><<<gemm_blocks, 256, 0, stream>>>(x, Wf1, P, tiles);
    aggregate_kernel<1><<<agg_blocks, 256, 0, stream>>>(P, offsets, csr_e, dinv, b1, X2, n);
    gemm_kernel<false><<<gemm_blocks, 256, 0, stream>>>(X2, Wf2, P, tiles);
    aggregate_kernel<0><<<agg_blocks, 256, 0, stream>>>(P, offsets, csr_e, dinv, b2, out, n);
}